// Round 1
// baseline (388.025 us; speedup 1.0000x reference)
//
#include <hip/hip_runtime.h>
#include <cstdint>
#include <cstddef>

#define NB 8
#define NTOK 2048
#define TOKENS (NB * NTOK)   // 16384
#define D 1024
#define E 64
#define CAP 40
#define EC (E * CAP)         // 2560
#define OUT_TENSOR ((size_t)TOKENS * EC)  // 41943040

// ---------------- Kernel 1: logits = x @ w  (fp32, LDS-tiled) ----------------
__global__ __launch_bounds__(256) void k_gemm(const float* __restrict__ x,
                                              const float* __restrict__ w,
                                              float* __restrict__ logits) {
  __shared__ float xs[64][33];   // padded to kill 32-float-stride bank conflicts
  __shared__ float wsh[32][64];
  const int tid = threadIdx.x;
  const int m0 = blockIdx.x * 64;
  const int tx = tid & 15;
  const int ty = tid >> 4;
  float acc[4][4];
#pragma unroll
  for (int i = 0; i < 4; ++i)
#pragma unroll
    for (int j = 0; j < 4; ++j) acc[i][j] = 0.f;

  for (int kc = 0; kc < D; kc += 32) {
#pragma unroll
    for (int i = 0; i < 2; ++i) {
      int flat = tid + i * 256;          // 0..511
      int row = flat >> 3;
      int c4 = (flat & 7) << 2;
      float4 v = *reinterpret_cast<const float4*>(&x[(size_t)(m0 + row) * D + kc + c4]);
      xs[row][c4 + 0] = v.x; xs[row][c4 + 1] = v.y;
      xs[row][c4 + 2] = v.z; xs[row][c4 + 3] = v.w;
    }
#pragma unroll
    for (int i = 0; i < 2; ++i) {
      int flat = tid + i * 256;
      int k = flat >> 4;
      int e = (flat & 15) << 2;
      *reinterpret_cast<float4*>(&wsh[k][e]) =
          *reinterpret_cast<const float4*>(&w[(size_t)(kc + k) * E + e]);
    }
    __syncthreads();
#pragma unroll
    for (int kk = 0; kk < 32; ++kk) {
      float4 bv = *reinterpret_cast<const float4*>(&wsh[kk][tx << 2]);
      float a0 = xs[(ty << 2) + 0][kk];
      float a1 = xs[(ty << 2) + 1][kk];
      float a2 = xs[(ty << 2) + 2][kk];
      float a3 = xs[(ty << 2) + 3][kk];
      acc[0][0] += a0 * bv.x; acc[0][1] += a0 * bv.y; acc[0][2] += a0 * bv.z; acc[0][3] += a0 * bv.w;
      acc[1][0] += a1 * bv.x; acc[1][1] += a1 * bv.y; acc[1][2] += a1 * bv.z; acc[1][3] += a1 * bv.w;
      acc[2][0] += a2 * bv.x; acc[2][1] += a2 * bv.y; acc[2][2] += a2 * bv.z; acc[2][3] += a2 * bv.w;
      acc[3][0] += a3 * bv.x; acc[3][1] += a3 * bv.y; acc[3][2] += a3 * bv.z; acc[3][3] += a3 * bv.w;
    }
    __syncthreads();
  }
#pragma unroll
  for (int i = 0; i < 4; ++i) {
    float4 v = make_float4(acc[i][0], acc[i][1], acc[i][2], acc[i][3]);
    *reinterpret_cast<float4*>(&logits[(size_t)(m0 + (ty << 2) + i) * E + (tx << 2)]) = v;
  }
}

// ------------- Kernel 2: softmax, top-2, routing decision, z/proxy -------------
__global__ __launch_bounds__(256) void k_gate(const float* __restrict__ logits,
                                              const float* __restrict__ noise,
                                              int* __restrict__ i1o, int* __restrict__ i2o,
                                              float* __restrict__ g1o, float* __restrict__ g2o,
                                              float* __restrict__ proxyacc,
                                              float* __restrict__ zpart) {
  const int wave = threadIdx.x >> 6;
  const int lane = threadIdx.x & 63;
  const int token = (blockIdx.x << 2) + wave;

  float l = logits[(size_t)token * E + lane];
  float m = l;
#pragma unroll
  for (int off = 32; off > 0; off >>= 1) m = fmaxf(m, __shfl_xor(m, off));
  float pe = expf(l - m);
  float s = pe;
#pragma unroll
  for (int off = 32; off > 0; off >>= 1) s += __shfl_xor(s, off);

  // top-1 on probabilities (ties -> lowest index, matching lax.top_k)
  float m1 = pe;
#pragma unroll
  for (int off = 32; off > 0; off >>= 1) m1 = fmaxf(m1, __shfl_xor(m1, off));
  int c1 = (pe == m1) ? lane : E;
#pragma unroll
  for (int off = 32; off > 0; off >>= 1) c1 = min(c1, __shfl_xor(c1, off));

  float pe2 = (lane == c1) ? -1.f : pe;
  float m2 = pe2;
#pragma unroll
  for (int off = 32; off > 0; off >>= 1) m2 = fmaxf(m2, __shfl_xor(m2, off));
  int c2 = (pe2 == m2) ? lane : E;
#pragma unroll
  for (int off = 32; off > 0; off >>= 1) c2 = min(c2, __shfl_xor(c2, off));

  float g1 = m1 / s;
  float g2 = m2 / s;
  float denom = g1 + g2 + 1e-9f;
  float g1n = g1 / denom;
  float g2n = g2 / denom;
  bool route = noise[token] < (g2n / 0.2f);

  if (lane == 0) {
    i1o[token] = c1;
    i2o[token] = route ? c2 : -1;
    g1o[token] = g1n;
    g2o[token] = g2n;
  }

  float lse = m + logf(s);
  float zsq = lse * lse;

  __shared__ float sm[4][64];
  __shared__ float zz[4];
  sm[wave][lane] = pe / s;
  if (lane == 0) zz[wave] = zsq;
  __syncthreads();
  if (wave == 0) {
    float sum4 = sm[0][lane] + sm[1][lane] + sm[2][lane] + sm[3][lane];
    atomicAdd(&proxyacc[(token >> 11) * E + lane], sum4);
    if (lane == 0) zpart[blockIdx.x] = zz[0] + zz[1] + zz[2] + zz[3];
  }
}

// ------------- Kernel 3: per-(batch,expert) exclusive cumsum positions -------------
// One block (64 lanes = 64 experts) per batch; sequential over 2048 tokens.
__global__ __launch_bounds__(64) void k_pos(const int* __restrict__ i1,
                                            const int* __restrict__ i2r,
                                            int* __restrict__ p1f, int* __restrict__ p2f,
                                            int* __restrict__ count1) {
  __shared__ int a1[NTOK];
  __shared__ int a2[NTOK];
  __shared__ int o1[NTOK];
  __shared__ int o2[NTOK];
  const int b = blockIdx.x;
  const int lane = threadIdx.x;
  for (int t = lane; t < NTOK; t += 64) {
    a1[t] = i1[b * NTOK + t];
    a2[t] = i2r[b * NTOK + t];
    o2[t] = -1;
  }
  __syncthreads();
  int c1 = 0, c2 = 0;
#pragma unroll 8
  for (int t = 0; t < NTOK; ++t) {
    int v1 = a1[t];
    if (v1 == lane) { o1[t] = (c1 < CAP) ? c1 : -1; c1++; }
    int v2 = a2[t];
    if (v2 == lane) { o2[t] = (c2 < CAP) ? c2 : -1; c2++; }
  }
  __syncthreads();
  for (int t = lane; t < NTOK; t += 64) {
    p1f[b * NTOK + t] = o1[t];
    p2f[b * NTOK + t] = o2[t];
  }
  count1[b * E + lane] = c1;   // pre-capacity top-1 counts (density_1)
}

// ------------- Kernel 4: scatter nonzeros into dispatch/combine -------------
__global__ __launch_bounds__(256) void k_scatter(const int* __restrict__ i1,
                                                 const int* __restrict__ i2r,
                                                 const float* __restrict__ g1,
                                                 const float* __restrict__ g2,
                                                 const int* __restrict__ p1f,
                                                 const int* __restrict__ p2f,
                                                 float* __restrict__ out) {
  const int t = blockIdx.x * 256 + threadIdx.x;
  if (t >= TOKENS) return;
  float* dispatch = out;
  float* combine = out + OUT_TENSOR;
  int e1 = i1[t], pp1 = p1f[t];
  if (pp1 >= 0) {
    size_t off = (size_t)t * EC + (size_t)e1 * CAP + pp1;
    float v = g1[t];
    combine[off] = v;
    dispatch[off] = (v != 0.f) ? 1.f : 0.f;
  }
  int e2 = i2r[t], pp2 = p2f[t];
  if (e2 >= 0 && pp2 >= 0) {
    size_t off = (size_t)t * EC + (size_t)e2 * CAP + pp2;
    float v = g2[t];
    combine[off] = v;
    dispatch[off] = (v != 0.f) ? 1.f : 0.f;
  }
}

// ------------- Kernel 5: finalize scalars -------------
__global__ __launch_bounds__(256) void k_final(const float* __restrict__ zpart,
                                               const float* __restrict__ proxyacc,
                                               const int* __restrict__ count1,
                                               float* __restrict__ out) {
  __shared__ float red[256];
  float zs = 0.f;
  for (int i = threadIdx.x; i < 4096; i += 256) zs += zpart[i];
  red[threadIdx.x] = zs;
  __syncthreads();
  for (int s = 128; s > 0; s >>= 1) {
    if (threadIdx.x < s) red[threadIdx.x] += red[threadIdx.x + s];
    __syncthreads();
  }
  float ztot = red[0];
  __syncthreads();
  float bs = 0.f;
  for (int i = threadIdx.x; i < 512; i += 256) bs += proxyacc[i] * (float)count1[i];
  red[threadIdx.x] = bs;
  __syncthreads();
  for (int s = 128; s > 0; s >>= 1) {
    if (threadIdx.x < s) red[threadIdx.x] += red[threadIdx.x + s];
    __syncthreads();
  }
  if (threadIdx.x == 0) {
    // balance = sum(proxySum*cnt) * e*e / (n*n*b*e) = sum / 524288
    out[2 * OUT_TENSOR] = red[0] / 524288.f;
    out[2 * OUT_TENSOR + 1] = ztot / 16384.f;
  }
}

extern "C" void kernel_launch(void* const* d_in, const int* in_sizes, int n_in,
                              void* d_out, int out_size, void* d_ws, size_t ws_size,
                              hipStream_t stream) {
  const float* x = (const float*)d_in[0];
  const float* w = (const float*)d_in[1];
  const float* noise = (const float*)d_in[2];
  float* out = (float*)d_out;

  float* ws = (float*)d_ws;
  float* logits = ws;                        // 16384*64
  int* i1 = (int*)(ws + 1048576);            // 16384
  int* i2r = i1 + TOKENS;                    // 16384
  float* g1 = (float*)(i2r + TOKENS);        // 16384
  float* g2 = g1 + TOKENS;                   // 16384
  int* p1f = (int*)(g2 + TOKENS);            // 16384
  int* p2f = p1f + TOKENS;                   // 16384
  float* proxyacc = (float*)(p2f + TOKENS);  // 512
  int* count1 = (int*)(proxyacc + 512);      // 512
  float* zpart = (float*)(count1 + 512);     // 4096

  hipMemsetAsync(d_out, 0, (size_t)out_size * sizeof(float), stream);
  hipMemsetAsync(proxyacc, 0, 512 * sizeof(float), stream);

  k_gemm<<<TOKENS / 64, 256, 0, stream>>>(x, w, logits);
  k_gate<<<TOKENS / 4, 256, 0, stream>>>(logits, noise, i1, i2r, g1, g2, proxyacc, zpart);
  k_pos<<<NB, 64, 0, stream>>>(i1, i2r, p1f, p2f, count1);
  k_scatter<<<TOKENS / 256, 256, 0, stream>>>(i1, i2r, g1, g2, p1f, p2f, out);
  k_final<<<1, 256, 0, stream>>>(zpart, proxyacc, count1, out);
}

// Round 2
// 177.722 us; speedup vs baseline: 2.1833x; 2.1833x over previous
//
#include <hip/hip_runtime.h>
#include <cstdint>
#include <cstddef>

#define NB 8
#define NTOK 2048
#define TOKENS (NB * NTOK)   // 16384
#define D 1024
#define E 64
#define CAP 40
#define EC (E * CAP)         // 2560
#define OUT_TENSOR ((size_t)TOKENS * EC)  // 41943040
#define CHUNKS 32            // per batch
#define CHTOK 64             // tokens per chunk

// ---------------- Kernel 1: logits = x @ w  (fp32, LDS-tiled) ----------------
__global__ __launch_bounds__(256) void k_gemm(const float* __restrict__ x,
                                              const float* __restrict__ w,
                                              float* __restrict__ logits) {
  __shared__ float xs[64][33];
  __shared__ float wsh[32][64];
  const int tid = threadIdx.x;
  const int m0 = blockIdx.x * 64;
  const int tx = tid & 15;
  const int ty = tid >> 4;
  float acc[4][4];
#pragma unroll
  for (int i = 0; i < 4; ++i)
#pragma unroll
    for (int j = 0; j < 4; ++j) acc[i][j] = 0.f;

  for (int kc = 0; kc < D; kc += 32) {
#pragma unroll
    for (int i = 0; i < 2; ++i) {
      int flat = tid + i * 256;
      int row = flat >> 3;
      int c4 = (flat & 7) << 2;
      float4 v = *reinterpret_cast<const float4*>(&x[(size_t)(m0 + row) * D + kc + c4]);
      xs[row][c4 + 0] = v.x; xs[row][c4 + 1] = v.y;
      xs[row][c4 + 2] = v.z; xs[row][c4 + 3] = v.w;
    }
#pragma unroll
    for (int i = 0; i < 2; ++i) {
      int flat = tid + i * 256;
      int k = flat >> 4;
      int e = (flat & 15) << 2;
      *reinterpret_cast<float4*>(&wsh[k][e]) =
          *reinterpret_cast<const float4*>(&w[(size_t)(kc + k) * E + e]);
    }
    __syncthreads();
#pragma unroll
    for (int kk = 0; kk < 32; ++kk) {
      float4 bv = *reinterpret_cast<const float4*>(&wsh[kk][tx << 2]);
      float a0 = xs[(ty << 2) + 0][kk];
      float a1 = xs[(ty << 2) + 1][kk];
      float a2 = xs[(ty << 2) + 2][kk];
      float a3 = xs[(ty << 2) + 3][kk];
      acc[0][0] += a0 * bv.x; acc[0][1] += a0 * bv.y; acc[0][2] += a0 * bv.z; acc[0][3] += a0 * bv.w;
      acc[1][0] += a1 * bv.x; acc[1][1] += a1 * bv.y; acc[1][2] += a1 * bv.z; acc[1][3] += a1 * bv.w;
      acc[2][0] += a2 * bv.x; acc[2][1] += a2 * bv.y; acc[2][2] += a2 * bv.z; acc[2][3] += a2 * bv.w;
      acc[3][0] += a3 * bv.x; acc[3][1] += a3 * bv.y; acc[3][2] += a3 * bv.z; acc[3][3] += a3 * bv.w;
    }
    __syncthreads();
  }
#pragma unroll
  for (int i = 0; i < 4; ++i) {
    float4 v = make_float4(acc[i][0], acc[i][1], acc[i][2], acc[i][3]);
    *reinterpret_cast<float4*>(&logits[(size_t)(m0 + (ty << 2) + i) * E + (tx << 2)]) = v;
  }
}

// ------------- Kernel 2: softmax, top-2, routing decision, z/proxy -------------
__global__ __launch_bounds__(256) void k_gate(const float* __restrict__ logits,
                                              const float* __restrict__ noise,
                                              int* __restrict__ i1o, int* __restrict__ i2o,
                                              float* __restrict__ g1o, float* __restrict__ g2o,
                                              float* __restrict__ proxyacc,
                                              float* __restrict__ zpart) {
  const int wave = threadIdx.x >> 6;
  const int lane = threadIdx.x & 63;
  const int token = (blockIdx.x << 2) + wave;

  float l = logits[(size_t)token * E + lane];
  float m = l;
#pragma unroll
  for (int off = 32; off > 0; off >>= 1) m = fmaxf(m, __shfl_xor(m, off));
  float pe = expf(l - m);
  float s = pe;
#pragma unroll
  for (int off = 32; off > 0; off >>= 1) s += __shfl_xor(s, off);

  float m1 = pe;
#pragma unroll
  for (int off = 32; off > 0; off >>= 1) m1 = fmaxf(m1, __shfl_xor(m1, off));
  int c1 = (pe == m1) ? lane : E;
#pragma unroll
  for (int off = 32; off > 0; off >>= 1) c1 = min(c1, __shfl_xor(c1, off));

  float pe2 = (lane == c1) ? -1.f : pe;
  float m2 = pe2;
#pragma unroll
  for (int off = 32; off > 0; off >>= 1) m2 = fmaxf(m2, __shfl_xor(m2, off));
  int c2 = (pe2 == m2) ? lane : E;
#pragma unroll
  for (int off = 32; off > 0; off >>= 1) c2 = min(c2, __shfl_xor(c2, off));

  float g1 = m1 / s;
  float g2 = m2 / s;
  float denom = g1 + g2 + 1e-9f;
  float g1n = g1 / denom;
  float g2n = g2 / denom;
  bool route = noise[token] < (g2n / 0.2f);

  if (lane == 0) {
    i1o[token] = c1;
    i2o[token] = route ? c2 : -1;
    g1o[token] = g1n;
    g2o[token] = g2n;
  }

  float lse = m + logf(s);
  float zsq = lse * lse;

  __shared__ float sm[4][64];
  __shared__ float zz[4];
  sm[wave][lane] = pe / s;
  if (lane == 0) zz[wave] = zsq;
  __syncthreads();
  if (wave == 0) {
    float sum4 = sm[0][lane] + sm[1][lane] + sm[2][lane] + sm[3][lane];
    atomicAdd(&proxyacc[(token >> 11) * E + lane], sum4);
    if (lane == 0) zpart[blockIdx.x] = zz[0] + zz[1] + zz[2] + zz[3];
  }
}

// ------------- Kernel 3: hierarchical parallel positions -------------
// One block per batch, 1024 threads = 16 waves; 32 chunks of 64 tokens.
// Step 1: per-chunk within-chunk positions + per-expert counts (ballot idiom).
// Step 2: exclusive prefix over chunk counts per expert.
// Step 3: final positions + capacity mask.
__global__ __launch_bounds__(1024) void k_pos(const int* __restrict__ i1,
                                              const int* __restrict__ i2r,
                                              int* __restrict__ p1f, int* __restrict__ p2f,
                                              int* __restrict__ count1) {
  __shared__ unsigned char pos1c[NTOK];
  __shared__ unsigned char pos2c[NTOK];
  __shared__ int cnt1[CHUNKS][E];
  __shared__ int cnt2[CHUNKS][E];

  const int b = blockIdx.x;
  const int tid = threadIdx.x;
  const int wave = tid >> 6;
  const int lane = tid & 63;
  const unsigned long long lt = (lane == 63) ? 0x7FFFFFFFFFFFFFFFull
                                             : ((1ull << lane) - 1ull);

  // Step 1: each wave handles chunks 2*wave and 2*wave+1
#pragma unroll
  for (int ci = 0; ci < 2; ++ci) {
    const int c = wave * 2 + ci;
    const int base = c * CHTOK;
    int e1 = i1[b * NTOK + base + lane];
    int e2 = i2r[b * NTOK + base + lane];
    int p1 = 0, p2 = 0, myc1 = 0, myc2 = 0;
    for (int e = 0; e < E; ++e) {
      unsigned long long m1 = __ballot(e1 == e);
      unsigned long long m2 = __ballot(e2 == e);
      if (e1 == e) p1 = __popcll(m1 & lt);
      if (e2 == e) p2 = __popcll(m2 & lt);
      if (lane == e) { myc1 = __popcll(m1); myc2 = __popcll(m2); }
    }
    pos1c[base + lane] = (unsigned char)p1;
    pos2c[base + lane] = (unsigned char)p2;
    cnt1[c][lane] = myc1;
    cnt2[c][lane] = myc2;
  }
  __syncthreads();

  // Step 2: exclusive prefix along chunks, per expert (threads 0..63)
  if (tid < E) {
    int run1 = 0, run2 = 0;
#pragma unroll 4
    for (int c = 0; c < CHUNKS; ++c) {
      int v1 = cnt1[c][tid]; cnt1[c][tid] = run1; run1 += v1;
      int v2 = cnt2[c][tid]; cnt2[c][tid] = run2; run2 += v2;
    }
    count1[b * E + tid] = run1;  // pre-capacity top-1 totals (density_1)
  }
  __syncthreads();

  // Step 3: final positions with capacity
#pragma unroll
  for (int ci = 0; ci < 2; ++ci) {
    const int c = wave * 2 + ci;
    const int base = c * CHTOK;
    const int t = b * NTOK + base + lane;
    int e1 = i1[t];
    int e2 = i2r[t];
    int pp1 = cnt1[c][e1] + (int)pos1c[base + lane];
    p1f[t] = (pp1 < CAP) ? pp1 : -1;
    int pp2 = -1;
    if (e2 >= 0) {
      pp2 = cnt2[c][e2] + (int)pos2c[base + lane];
      if (pp2 >= CAP) pp2 = -1;
    }
    p2f[t] = pp2;
  }
}

// ------------- Kernel 4: scatter nonzeros into dispatch/combine -------------
__global__ __launch_bounds__(256) void k_scatter(const int* __restrict__ i1,
                                                 const int* __restrict__ i2r,
                                                 const float* __restrict__ g1,
                                                 const float* __restrict__ g2,
                                                 const int* __restrict__ p1f,
                                                 const int* __restrict__ p2f,
                                                 float* __restrict__ out) {
  const int t = blockIdx.x * 256 + threadIdx.x;
  if (t >= TOKENS) return;
  float* dispatch = out;
  float* combine = out + OUT_TENSOR;
  int e1 = i1[t], pp1 = p1f[t];
  if (pp1 >= 0) {
    size_t off = (size_t)t * EC + (size_t)e1 * CAP + pp1;
    float v = g1[t];
    combine[off] = v;
    dispatch[off] = (v != 0.f) ? 1.f : 0.f;
  }
  int e2 = i2r[t], pp2 = p2f[t];
  if (e2 >= 0 && pp2 >= 0) {
    size_t off = (size_t)t * EC + (size_t)e2 * CAP + pp2;
    float v = g2[t];
    combine[off] = v;
    dispatch[off] = (v != 0.f) ? 1.f : 0.f;
  }
}

// ------------- Kernel 5: finalize scalars -------------
__global__ __launch_bounds__(256) void k_final(const float* __restrict__ zpart,
                                               const float* __restrict__ proxyacc,
                                               const int* __restrict__ count1,
                                               float* __restrict__ out) {
  __shared__ float red[256];
  float zs = 0.f;
  for (int i = threadIdx.x; i < 4096; i += 256) zs += zpart[i];
  red[threadIdx.x] = zs;
  __syncthreads();
  for (int s = 128; s > 0; s >>= 1) {
    if (threadIdx.x < s) red[threadIdx.x] += red[threadIdx.x + s];
    __syncthreads();
  }
  float ztot = red[0];
  __syncthreads();
  float bs = 0.f;
  for (int i = threadIdx.x; i < 512; i += 256) bs += proxyacc[i] * (float)count1[i];
  red[threadIdx.x] = bs;
  __syncthreads();
  for (int s = 128; s > 0; s >>= 1) {
    if (threadIdx.x < s) red[threadIdx.x] += red[threadIdx.x + s];
    __syncthreads();
  }
  if (threadIdx.x == 0) {
    out[2 * OUT_TENSOR] = red[0] / 524288.f;
    out[2 * OUT_TENSOR + 1] = ztot / 16384.f;
  }
}

extern "C" void kernel_launch(void* const* d_in, const int* in_sizes, int n_in,
                              void* d_out, int out_size, void* d_ws, size_t ws_size,
                              hipStream_t stream) {
  const float* x = (const float*)d_in[0];
  const float* w = (const float*)d_in[1];
  const float* noise = (const float*)d_in[2];
  float* out = (float*)d_out;

  float* ws = (float*)d_ws;
  float* logits = ws;                        // 16384*64
  int* i1 = (int*)(ws + 1048576);            // 16384
  int* i2r = i1 + TOKENS;                    // 16384
  float* g1 = (float*)(i2r + TOKENS);        // 16384
  float* g2 = g1 + TOKENS;                   // 16384
  int* p1f = (int*)(g2 + TOKENS);            // 16384
  int* p2f = p1f + TOKENS;                   // 16384
  float* proxyacc = (float*)(p2f + TOKENS);  // 512
  int* count1 = (int*)(proxyacc + 512);      // 512
  float* zpart = (float*)(count1 + 512);     // 4096

  hipMemsetAsync(d_out, 0, (size_t)out_size * sizeof(float), stream);
  hipMemsetAsync(proxyacc, 0, 512 * sizeof(float), stream);

  k_gemm<<<TOKENS / 64, 256, 0, stream>>>(x, w, logits);
  k_gate<<<TOKENS / 4, 256, 0, stream>>>(logits, noise, i1, i2r, g1, g2, proxyacc, zpart);
  k_pos<<<NB, 1024, 0, stream>>>(i1, i2r, p1f, p2f, count1);
  k_scatter<<<TOKENS / 256, 256, 0, stream>>>(i1, i2r, g1, g2, p1f, p2f, out);
  k_final<<<1, 256, 0, stream>>>(zpart, proxyacc, count1, out);
}

// Round 3
// 161.956 us; speedup vs baseline: 2.3959x; 1.0973x over previous
//
#include <hip/hip_runtime.h>
#include <cstdint>
#include <cstddef>

#define NB 8
#define NTOK 2048
#define TOKENS (NB * NTOK)   // 16384
#define D 1024
#define E 64
#define CAP 40
#define EC (E * CAP)         // 2560
#define OUT_TENSOR ((size_t)TOKENS * EC)  // 41943040
#define CHUNKS 32            // per batch
#define CHTOK 64             // tokens per chunk

#define GEMM_BLOCKS 256
#define FILL_BLOCKS 768
#define TOTAL_F4 ((2 * OUT_TENSOR) / 4)   // 20,971,520 float4 covering both tensors

// ---------------- Kernel A: [gemm blocks || zero-fill blocks] ----------------
// Blocks 0..255: logits = x @ w (fp32, LDS-tiled) — body kept BIT-IDENTICAL to
// the validated round-1 kernel (same tiles, same accumulation order) so the
// logits, and hence all routing decisions, are unchanged.
// Blocks 256..1023: grid-stride float4 zero-fill of the 335.5 MB output
// (runs concurrently with the GEMM on the store pipe; block 256 also zeroes
// proxyacc, replacing the second memset).
__global__ __launch_bounds__(256) void k_gemm_fill(const float* __restrict__ x,
                                                   const float* __restrict__ w,
                                                   float* __restrict__ logits,
                                                   float* __restrict__ out,
                                                   float* __restrict__ proxyacc) {
  __shared__ float xs[64][33];
  __shared__ float wsh[32][64];
  const int tid = threadIdx.x;

  if (blockIdx.x >= GEMM_BLOCKS) {
    // ---------------- zero-fill path ----------------
    if (blockIdx.x == GEMM_BLOCKS && tid < 128) {
      float4 z = make_float4(0.f, 0.f, 0.f, 0.f);
      reinterpret_cast<float4*>(proxyacc)[tid] = z;  // 512 floats
    }
    float4* o4 = reinterpret_cast<float4*>(out);
    const size_t start = (size_t)(blockIdx.x - GEMM_BLOCKS) * 256 + tid;
    const size_t stride = (size_t)FILL_BLOCKS * 256;
    float4 z = make_float4(0.f, 0.f, 0.f, 0.f);
    for (size_t q = start; q < TOTAL_F4; q += stride) o4[q] = z;
    return;
  }

  // ---------------- GEMM path (verbatim from round 1) ----------------
  const int m0 = blockIdx.x * 64;
  const int tx = tid & 15;
  const int ty = tid >> 4;
  float acc[4][4];
#pragma unroll
  for (int i = 0; i < 4; ++i)
#pragma unroll
    for (int j = 0; j < 4; ++j) acc[i][j] = 0.f;

  for (int kc = 0; kc < D; kc += 32) {
#pragma unroll
    for (int i = 0; i < 2; ++i) {
      int flat = tid + i * 256;
      int row = flat >> 3;
      int c4 = (flat & 7) << 2;
      float4 v = *reinterpret_cast<const float4*>(&x[(size_t)(m0 + row) * D + kc + c4]);
      xs[row][c4 + 0] = v.x; xs[row][c4 + 1] = v.y;
      xs[row][c4 + 2] = v.z; xs[row][c4 + 3] = v.w;
    }
#pragma unroll
    for (int i = 0; i < 2; ++i) {
      int flat = tid + i * 256;
      int k = flat >> 4;
      int e = (flat & 15) << 2;
      *reinterpret_cast<float4*>(&wsh[k][e]) =
          *reinterpret_cast<const float4*>(&w[(size_t)(kc + k) * E + e]);
    }
    __syncthreads();
#pragma unroll
    for (int kk = 0; kk < 32; ++kk) {
      float4 bv = *reinterpret_cast<const float4*>(&wsh[kk][tx << 2]);
      float a0 = xs[(ty << 2) + 0][kk];
      float a1 = xs[(ty << 2) + 1][kk];
      float a2 = xs[(ty << 2) + 2][kk];
      float a3 = xs[(ty << 2) + 3][kk];
      acc[0][0] += a0 * bv.x; acc[0][1] += a0 * bv.y; acc[0][2] += a0 * bv.z; acc[0][3] += a0 * bv.w;
      acc[1][0] += a1 * bv.x; acc[1][1] += a1 * bv.y; acc[1][2] += a1 * bv.z; acc[1][3] += a1 * bv.w;
      acc[2][0] += a2 * bv.x; acc[2][1] += a2 * bv.y; acc[2][2] += a2 * bv.z; acc[2][3] += a2 * bv.w;
      acc[3][0] += a3 * bv.x; acc[3][1] += a3 * bv.y; acc[3][2] += a3 * bv.z; acc[3][3] += a3 * bv.w;
    }
    __syncthreads();
  }
#pragma unroll
  for (int i = 0; i < 4; ++i) {
    float4 v = make_float4(acc[i][0], acc[i][1], acc[i][2], acc[i][3]);
    *reinterpret_cast<float4*>(&logits[(size_t)(m0 + (ty << 2) + i) * E + (tx << 2)]) = v;
  }
}

// ------------- Kernel 2: softmax, top-2, routing decision, z/proxy -------------
__global__ __launch_bounds__(256) void k_gate(const float* __restrict__ logits,
                                              const float* __restrict__ noise,
                                              int* __restrict__ i1o, int* __restrict__ i2o,
                                              float* __restrict__ g1o, float* __restrict__ g2o,
                                              float* __restrict__ proxyacc,
                                              float* __restrict__ zpart) {
  const int wave = threadIdx.x >> 6;
  const int lane = threadIdx.x & 63;
  const int token = (blockIdx.x << 2) + wave;

  float l = logits[(size_t)token * E + lane];
  float m = l;
#pragma unroll
  for (int off = 32; off > 0; off >>= 1) m = fmaxf(m, __shfl_xor(m, off));
  float pe = expf(l - m);
  float s = pe;
#pragma unroll
  for (int off = 32; off > 0; off >>= 1) s += __shfl_xor(s, off);

  float m1 = pe;
#pragma unroll
  for (int off = 32; off > 0; off >>= 1) m1 = fmaxf(m1, __shfl_xor(m1, off));
  int c1 = (pe == m1) ? lane : E;
#pragma unroll
  for (int off = 32; off > 0; off >>= 1) c1 = min(c1, __shfl_xor(c1, off));

  float pe2 = (lane == c1) ? -1.f : pe;
  float m2 = pe2;
#pragma unroll
  for (int off = 32; off > 0; off >>= 1) m2 = fmaxf(m2, __shfl_xor(m2, off));
  int c2 = (pe2 == m2) ? lane : E;
#pragma unroll
  for (int off = 32; off > 0; off >>= 1) c2 = min(c2, __shfl_xor(c2, off));

  float g1 = m1 / s;
  float g2 = m2 / s;
  float denom = g1 + g2 + 1e-9f;
  float g1n = g1 / denom;
  float g2n = g2 / denom;
  bool route = noise[token] < (g2n / 0.2f);

  if (lane == 0) {
    i1o[token] = c1;
    i2o[token] = route ? c2 : -1;
    g1o[token] = g1n;
    g2o[token] = g2n;
  }

  float lse = m + logf(s);
  float zsq = lse * lse;

  __shared__ float sm[4][64];
  __shared__ float zz[4];
  sm[wave][lane] = pe / s;
  if (lane == 0) zz[wave] = zsq;
  __syncthreads();
  if (wave == 0) {
    float sum4 = sm[0][lane] + sm[1][lane] + sm[2][lane] + sm[3][lane];
    atomicAdd(&proxyacc[(token >> 11) * E + lane], sum4);
    if (lane == 0) zpart[blockIdx.x] = zz[0] + zz[1] + zz[2] + zz[3];
  }
}

// ------------- Kernel 3: hierarchical parallel positions -------------
__global__ __launch_bounds__(1024) void k_pos(const int* __restrict__ i1,
                                              const int* __restrict__ i2r,
                                              int* __restrict__ p1f, int* __restrict__ p2f,
                                              int* __restrict__ count1) {
  __shared__ unsigned char pos1c[NTOK];
  __shared__ unsigned char pos2c[NTOK];
  __shared__ int cnt1[CHUNKS][E];
  __shared__ int cnt2[CHUNKS][E];

  const int b = blockIdx.x;
  const int tid = threadIdx.x;
  const int wave = tid >> 6;
  const int lane = tid & 63;
  const unsigned long long lt = (lane == 63) ? 0x7FFFFFFFFFFFFFFFull
                                             : ((1ull << lane) - 1ull);

#pragma unroll
  for (int ci = 0; ci < 2; ++ci) {
    const int c = wave * 2 + ci;
    const int base = c * CHTOK;
    int e1 = i1[b * NTOK + base + lane];
    int e2 = i2r[b * NTOK + base + lane];
    int p1 = 0, p2 = 0, myc1 = 0, myc2 = 0;
    for (int e = 0; e < E; ++e) {
      unsigned long long m1 = __ballot(e1 == e);
      unsigned long long m2 = __ballot(e2 == e);
      if (e1 == e) p1 = __popcll(m1 & lt);
      if (e2 == e) p2 = __popcll(m2 & lt);
      if (lane == e) { myc1 = __popcll(m1); myc2 = __popcll(m2); }
    }
    pos1c[base + lane] = (unsigned char)p1;
    pos2c[base + lane] = (unsigned char)p2;
    cnt1[c][lane] = myc1;
    cnt2[c][lane] = myc2;
  }
  __syncthreads();

  if (tid < E) {
    int run1 = 0, run2 = 0;
#pragma unroll 4
    for (int c = 0; c < CHUNKS; ++c) {
      int v1 = cnt1[c][tid]; cnt1[c][tid] = run1; run1 += v1;
      int v2 = cnt2[c][tid]; cnt2[c][tid] = run2; run2 += v2;
    }
    count1[b * E + tid] = run1;
  }
  __syncthreads();

#pragma unroll
  for (int ci = 0; ci < 2; ++ci) {
    const int c = wave * 2 + ci;
    const int base = c * CHTOK;
    const int t = b * NTOK + base + lane;
    int e1 = i1[t];
    int e2 = i2r[t];
    int pp1 = cnt1[c][e1] + (int)pos1c[base + lane];
    p1f[t] = (pp1 < CAP) ? pp1 : -1;
    int pp2 = -1;
    if (e2 >= 0) {
      pp2 = cnt2[c][e2] + (int)pos2c[base + lane];
      if (pp2 >= CAP) pp2 = -1;
    }
    p2f[t] = pp2;
  }
}

// ------------- Kernel 4: scatter nonzeros into dispatch/combine -------------
__global__ __launch_bounds__(256) void k_scatter(const int* __restrict__ i1,
                                                 const int* __restrict__ i2r,
                                                 const float* __restrict__ g1,
                                                 const float* __restrict__ g2,
                                                 const int* __restrict__ p1f,
                                                 const int* __restrict__ p2f,
                                                 float* __restrict__ out) {
  const int t = blockIdx.x * 256 + threadIdx.x;
  if (t >= TOKENS) return;
  float* dispatch = out;
  float* combine = out + OUT_TENSOR;
  int e1 = i1[t], pp1 = p1f[t];
  if (pp1 >= 0) {
    size_t off = (size_t)t * EC + (size_t)e1 * CAP + pp1;
    float v = g1[t];
    combine[off] = v;
    dispatch[off] = (v != 0.f) ? 1.f : 0.f;
  }
  int e2 = i2r[t], pp2 = p2f[t];
  if (e2 >= 0 && pp2 >= 0) {
    size_t off = (size_t)t * EC + (size_t)e2 * CAP + pp2;
    float v = g2[t];
    combine[off] = v;
    dispatch[off] = (v != 0.f) ? 1.f : 0.f;
  }
}

// ------------- Kernel 5: finalize scalars -------------
__global__ __launch_bounds__(256) void k_final(const float* __restrict__ zpart,
                                               const float* __restrict__ proxyacc,
                                               const int* __restrict__ count1,
                                               float* __restrict__ out) {
  __shared__ float red[256];
  float zs = 0.f;
  for (int i = threadIdx.x; i < 4096; i += 256) zs += zpart[i];
  red[threadIdx.x] = zs;
  __syncthreads();
  for (int s = 128; s > 0; s >>= 1) {
    if (threadIdx.x < s) red[threadIdx.x] += red[threadIdx.x + s];
    __syncthreads();
  }
  float ztot = red[0];
  __syncthreads();
  float bs = 0.f;
  for (int i = threadIdx.x; i < 512; i += 256) bs += proxyacc[i] * (float)count1[i];
  red[threadIdx.x] = bs;
  __syncthreads();
  for (int s = 128; s > 0; s >>= 1) {
    if (threadIdx.x < s) red[threadIdx.x] += red[threadIdx.x + s];
    __syncthreads();
  }
  if (threadIdx.x == 0) {
    out[2 * OUT_TENSOR] = red[0] / 524288.f;
    out[2 * OUT_TENSOR + 1] = ztot / 16384.f;
  }
}

extern "C" void kernel_launch(void* const* d_in, const int* in_sizes, int n_in,
                              void* d_out, int out_size, void* d_ws, size_t ws_size,
                              hipStream_t stream) {
  const float* x = (const float*)d_in[0];
  const float* w = (const float*)d_in[1];
  const float* noise = (const float*)d_in[2];
  float* out = (float*)d_out;

  float* ws = (float*)d_ws;
  float* logits = ws;                        // 16384*64
  int* i1 = (int*)(ws + 1048576);            // 16384
  int* i2r = i1 + TOKENS;                    // 16384
  float* g1 = (float*)(i2r + TOKENS);        // 16384
  float* g2 = g1 + TOKENS;                   // 16384
  int* p1f = (int*)(g2 + TOKENS);            // 16384
  int* p2f = p1f + TOKENS;                   // 16384
  float* proxyacc = (float*)(p2f + TOKENS);  // 512
  int* count1 = (int*)(proxyacc + 512);      // 512
  float* zpart = (float*)(count1 + 512);     // 4096

  k_gemm_fill<<<GEMM_BLOCKS + FILL_BLOCKS, 256, 0, stream>>>(x, w, logits, out, proxyacc);
  k_gate<<<TOKENS / 4, 256, 0, stream>>>(logits, noise, i1, i2r, g1, g2, proxyacc, zpart);
  k_pos<<<NB, 1024, 0, stream>>>(i1, i2r, p1f, p2f, count1);
  k_scatter<<<TOKENS / 256, 256, 0, stream>>>(i1, i2r, g1, g2, p1f, p2f, out);
  k_final<<<1, 256, 0, stream>>>(zpart, proxyacc, count1, out);
}

// Round 4
// 158.088 us; speedup vs baseline: 2.4545x; 1.0245x over previous
//
#include <hip/hip_runtime.h>
#include <cstdint>
#include <cstddef>

#define NB 8
#define NTOK 2048
#define TOKENS (NB * NTOK)   // 16384
#define D 1024
#define E 64
#define CAP 40
#define EC (E * CAP)         // 2560
#define OUT_TENSOR ((size_t)TOKENS * EC)  // 41943040
#define CHUNKS 32            // per batch
#define CHTOK 64             // tokens per chunk

#define GEMM_BLOCKS 256
#define FILL_BLOCKS 768
#define TOTAL_F4 ((2 * OUT_TENSOR) / 4)   // 20,971,520 float4 covering both tensors

// ---------------- Kernel A: [gemm blocks || zero-fill blocks] ----------------
// GEMM path: logits = x @ w, fp32, LDS-tiled. Values and per-element FMA
// accumulation order are IDENTICAL to the validated round-1 kernel (same k
// order, same operands) -> bit-identical logits. Only the LDS layout changed:
// A stored transposed (AsT[k][row], stride 68 floats = 272 B, 16B-aligned) so
// the inner loop is 2x ds_read_b128 per kk instead of 4x ds_read_b32 + b128.
// Fill path: blocks 256..1023 zero the 335.5 MB output concurrently.
__global__ __launch_bounds__(256) void k_gemm_fill(const float* __restrict__ x,
                                                   const float* __restrict__ w,
                                                   float* __restrict__ logits,
                                                   float* __restrict__ out,
                                                   float* __restrict__ proxyacc) {
  __shared__ float AsT[32][68];   // [k][row], padded: reads conflict-free, 16B aligned
  __shared__ float Bsh[32][68];   // [k][n],  padded
  const int tid = threadIdx.x;

  if (blockIdx.x >= GEMM_BLOCKS) {
    // ---------------- zero-fill path ----------------
    if (blockIdx.x == GEMM_BLOCKS && tid < 128) {
      float4 z = make_float4(0.f, 0.f, 0.f, 0.f);
      reinterpret_cast<float4*>(proxyacc)[tid] = z;  // 512 floats
    }
    float4* o4 = reinterpret_cast<float4*>(out);
    const size_t start = (size_t)(blockIdx.x - GEMM_BLOCKS) * 256 + tid;
    const size_t stride = (size_t)FILL_BLOCKS * 256;
    float4 z = make_float4(0.f, 0.f, 0.f, 0.f);
    for (size_t q = start; q < TOTAL_F4; q += stride) o4[q] = z;
    return;
  }

  // ---------------- GEMM path ----------------
  const int m0 = blockIdx.x * 64;
  const int tx = tid & 15;
  const int ty = tid >> 4;
  float acc[4][4];
#pragma unroll
  for (int i = 0; i < 4; ++i)
#pragma unroll
    for (int j = 0; j < 4; ++j) acc[i][j] = 0.f;

  for (int kc = 0; kc < D; kc += 32) {
    // stage x tile transposed: AsT[k][row] = x[m0+row][kc+k]
#pragma unroll
    for (int i = 0; i < 2; ++i) {
      int q = tid + i * 256;           // 0..511
      int row = q >> 3;                // 64 rows
      int k4 = (q & 7) << 2;           // 8 float4 per row
      float4 v = *reinterpret_cast<const float4*>(&x[(size_t)(m0 + row) * D + kc + k4]);
      AsT[k4 + 0][row] = v.x; AsT[k4 + 1][row] = v.y;
      AsT[k4 + 2][row] = v.z; AsT[k4 + 3][row] = v.w;
    }
    // stage w tile: Bsh[k][n] = w[kc+k][n]
#pragma unroll
    for (int i = 0; i < 2; ++i) {
      int q = tid + i * 256;
      int k = q >> 4;
      int n4 = (q & 15) << 2;
      *reinterpret_cast<float4*>(&Bsh[k][n4]) =
          *reinterpret_cast<const float4*>(&w[(size_t)(kc + k) * E + n4]);
    }
    __syncthreads();
#pragma unroll
    for (int kk = 0; kk < 32; ++kk) {
      float4 av = *reinterpret_cast<const float4*>(&AsT[kk][ty << 2]);  // 4 rows
      float4 bv = *reinterpret_cast<const float4*>(&Bsh[kk][tx << 2]);  // 4 cols
      acc[0][0] += av.x * bv.x; acc[0][1] += av.x * bv.y; acc[0][2] += av.x * bv.z; acc[0][3] += av.x * bv.w;
      acc[1][0] += av.y * bv.x; acc[1][1] += av.y * bv.y; acc[1][2] += av.y * bv.z; acc[1][3] += av.y * bv.w;
      acc[2][0] += av.z * bv.x; acc[2][1] += av.z * bv.y; acc[2][2] += av.z * bv.z; acc[2][3] += av.z * bv.w;
      acc[3][0] += av.w * bv.x; acc[3][1] += av.w * bv.y; acc[3][2] += av.w * bv.z; acc[3][3] += av.w * bv.w;
    }
    __syncthreads();
  }
#pragma unroll
  for (int i = 0; i < 4; ++i) {
    float4 v = make_float4(acc[i][0], acc[i][1], acc[i][2], acc[i][3]);
    *reinterpret_cast<float4*>(&logits[(size_t)(m0 + (ty << 2) + i) * E + (tx << 2)]) = v;
  }
}

// ------------- Kernel 2: softmax, top-2, routing decision, z/proxy -------------
__global__ __launch_bounds__(256) void k_gate(const float* __restrict__ logits,
                                              const float* __restrict__ noise,
                                              int* __restrict__ i1o, int* __restrict__ i2o,
                                              float* __restrict__ g1o, float* __restrict__ g2o,
                                              float* __restrict__ proxyacc,
                                              float* __restrict__ zpart) {
  const int wave = threadIdx.x >> 6;
  const int lane = threadIdx.x & 63;
  const int token = (blockIdx.x << 2) + wave;

  float l = logits[(size_t)token * E + lane];
  float m = l;
#pragma unroll
  for (int off = 32; off > 0; off >>= 1) m = fmaxf(m, __shfl_xor(m, off));
  float pe = expf(l - m);
  float s = pe;
#pragma unroll
  for (int off = 32; off > 0; off >>= 1) s += __shfl_xor(s, off);

  float m1 = pe;
#pragma unroll
  for (int off = 32; off > 0; off >>= 1) m1 = fmaxf(m1, __shfl_xor(m1, off));
  int c1 = (pe == m1) ? lane : E;
#pragma unroll
  for (int off = 32; off > 0; off >>= 1) c1 = min(c1, __shfl_xor(c1, off));

  float pe2 = (lane == c1) ? -1.f : pe;
  float m2 = pe2;
#pragma unroll
  for (int off = 32; off > 0; off >>= 1) m2 = fmaxf(m2, __shfl_xor(m2, off));
  int c2 = (pe2 == m2) ? lane : E;
#pragma unroll
  for (int off = 32; off > 0; off >>= 1) c2 = min(c2, __shfl_xor(c2, off));

  float g1 = m1 / s;
  float g2 = m2 / s;
  float denom = g1 + g2 + 1e-9f;
  float g1n = g1 / denom;
  float g2n = g2 / denom;
  bool route = noise[token] < (g2n / 0.2f);

  if (lane == 0) {
    i1o[token] = c1;
    i2o[token] = route ? c2 : -1;
    g1o[token] = g1n;
    g2o[token] = g2n;
  }

  float lse = m + logf(s);
  float zsq = lse * lse;

  __shared__ float sm[4][64];
  __shared__ float zz[4];
  sm[wave][lane] = pe / s;
  if (lane == 0) zz[wave] = zsq;
  __syncthreads();
  if (wave == 0) {
    float sum4 = sm[0][lane] + sm[1][lane] + sm[2][lane] + sm[3][lane];
    atomicAdd(&proxyacc[(token >> 11) * E + lane], sum4);
    if (lane == 0) zpart[blockIdx.x] = zz[0] + zz[1] + zz[2] + zz[3];
  }
}

// ------------- Kernel 3: hierarchical parallel positions -------------
__global__ __launch_bounds__(1024) void k_pos(const int* __restrict__ i1,
                                              const int* __restrict__ i2r,
                                              int* __restrict__ p1f, int* __restrict__ p2f,
                                              int* __restrict__ count1) {
  __shared__ unsigned char pos1c[NTOK];
  __shared__ unsigned char pos2c[NTOK];
  __shared__ int cnt1[CHUNKS][E];
  __shared__ int cnt2[CHUNKS][E];

  const int b = blockIdx.x;
  const int tid = threadIdx.x;
  const int wave = tid >> 6;
  const int lane = tid & 63;
  const unsigned long long lt = (lane == 63) ? 0x7FFFFFFFFFFFFFFFull
                                             : ((1ull << lane) - 1ull);

#pragma unroll
  for (int ci = 0; ci < 2; ++ci) {
    const int c = wave * 2 + ci;
    const int base = c * CHTOK;
    int e1 = i1[b * NTOK + base + lane];
    int e2 = i2r[b * NTOK + base + lane];
    int p1 = 0, p2 = 0, myc1 = 0, myc2 = 0;
    for (int e = 0; e < E; ++e) {
      unsigned long long m1 = __ballot(e1 == e);
      unsigned long long m2 = __ballot(e2 == e);
      if (e1 == e) p1 = __popcll(m1 & lt);
      if (e2 == e) p2 = __popcll(m2 & lt);
      if (lane == e) { myc1 = __popcll(m1); myc2 = __popcll(m2); }
    }
    pos1c[base + lane] = (unsigned char)p1;
    pos2c[base + lane] = (unsigned char)p2;
    cnt1[c][lane] = myc1;
    cnt2[c][lane] = myc2;
  }
  __syncthreads();

  if (tid < E) {
    int run1 = 0, run2 = 0;
#pragma unroll 4
    for (int c = 0; c < CHUNKS; ++c) {
      int v1 = cnt1[c][tid]; cnt1[c][tid] = run1; run1 += v1;
      int v2 = cnt2[c][tid]; cnt2[c][tid] = run2; run2 += v2;
    }
    count1[b * E + tid] = run1;
  }
  __syncthreads();

#pragma unroll
  for (int ci = 0; ci < 2; ++ci) {
    const int c = wave * 2 + ci;
    const int base = c * CHTOK;
    const int t = b * NTOK + base + lane;
    int e1 = i1[t];
    int e2 = i2r[t];
    int pp1 = cnt1[c][e1] + (int)pos1c[base + lane];
    p1f[t] = (pp1 < CAP) ? pp1 : -1;
    int pp2 = -1;
    if (e2 >= 0) {
      pp2 = cnt2[c][e2] + (int)pos2c[base + lane];
      if (pp2 >= CAP) pp2 = -1;
    }
    p2f[t] = pp2;
  }
}

// ------------- Kernel 4: scatter nonzeros into dispatch/combine -------------
__global__ __launch_bounds__(256) void k_scatter(const int* __restrict__ i1,
                                                 const int* __restrict__ i2r,
                                                 const float* __restrict__ g1,
                                                 const float* __restrict__ g2,
                                                 const int* __restrict__ p1f,
                                                 const int* __restrict__ p2f,
                                                 float* __restrict__ out) {
  const int t = blockIdx.x * 256 + threadIdx.x;
  if (t >= TOKENS) return;
  float* dispatch = out;
  float* combine = out + OUT_TENSOR;
  int e1 = i1[t], pp1 = p1f[t];
  if (pp1 >= 0) {
    size_t off = (size_t)t * EC + (size_t)e1 * CAP + pp1;
    float v = g1[t];
    combine[off] = v;
    dispatch[off] = (v != 0.f) ? 1.f : 0.f;
  }
  int e2 = i2r[t], pp2 = p2f[t];
  if (e2 >= 0 && pp2 >= 0) {
    size_t off = (size_t)t * EC + (size_t)e2 * CAP + pp2;
    float v = g2[t];
    combine[off] = v;
    dispatch[off] = (v != 0.f) ? 1.f : 0.f;
  }
}

// ------------- Kernel 5: finalize scalars -------------
__global__ __launch_bounds__(256) void k_final(const float* __restrict__ zpart,
                                               const float* __restrict__ proxyacc,
                                               const int* __restrict__ count1,
                                               float* __restrict__ out) {
  __shared__ float red[256];
  float zs = 0.f;
  for (int i = threadIdx.x; i < 4096; i += 256) zs += zpart[i];
  red[threadIdx.x] = zs;
  __syncthreads();
  for (int s = 128; s > 0; s >>= 1) {
    if (threadIdx.x < s) red[threadIdx.x] += red[threadIdx.x + s];
    __syncthreads();
  }
  float ztot = red[0];
  __syncthreads();
  float bs = 0.f;
  for (int i = threadIdx.x; i < 512; i += 256) bs += proxyacc[i] * (float)count1[i];
  red[threadIdx.x] = bs;
  __syncthreads();
  for (int s = 128; s > 0; s >>= 1) {
    if (threadIdx.x < s) red[threadIdx.x] += red[threadIdx.x + s];
    __syncthreads();
  }
  if (threadIdx.x == 0) {
    out[2 * OUT_TENSOR] = red[0] / 524288.f;
    out[2 * OUT_TENSOR + 1] = ztot / 16384.f;
  }
}

extern "C" void kernel_launch(void* const* d_in, const int* in_sizes, int n_in,
                              void* d_out, int out_size, void* d_ws, size_t ws_size,
                              hipStream_t stream) {
  const float* x = (const float*)d_in[0];
  const float* w = (const float*)d_in[1];
  const float* noise = (const float*)d_in[2];
  float* out = (float*)d_out;

  float* ws = (float*)d_ws;
  float* logits = ws;                        // 16384*64
  int* i1 = (int*)(ws + 1048576);            // 16384
  int* i2r = i1 + TOKENS;                    // 16384
  float* g1 = (float*)(i2r + TOKENS);        // 16384
  float* g2 = g1 + TOKENS;                   // 16384
  int* p1f = (int*)(g2 + TOKENS);            // 16384
  int* p2f = p1f + TOKENS;                   // 16384
  float* proxyacc = (float*)(p2f + TOKENS);  // 512
  int* count1 = (int*)(proxyacc + 512);      // 512
  float* zpart = (float*)(count1 + 512);     // 4096

  k_gemm_fill<<<GEMM_BLOCKS + FILL_BLOCKS, 256, 0, stream>>>(x, w, logits, out, proxyacc);
  k_gate<<<TOKENS / 4, 256, 0, stream>>>(logits, noise, i1, i2r, g1, g2, proxyacc, zpart);
  k_pos<<<NB, 1024, 0, stream>>>(i1, i2r, p1f, p2f, count1);
  k_scatter<<<TOKENS / 256, 256, 0, stream>>>(i1, i2r, g1, g2, p1f, p2f, out);
  k_final<<<1, 256, 0, stream>>>(zpart, proxyacc, count1, out);
}

// Round 5
// 138.675 us; speedup vs baseline: 2.7981x; 1.1400x over previous
//
#include <hip/hip_runtime.h>
#include <cstdint>
#include <cstddef>

#define NB 8
#define NTOK 2048
#define TOKENS (NB * NTOK)   // 16384
#define D 1024
#define E 64
#define CAP 40
#define EC (E * CAP)         // 2560
#define OUT_TENSOR ((size_t)TOKENS * EC)  // 41943040
#define CHUNKS 32            // per batch (k_pos)
#define CHTOK 64             // tokens per chunk (k_pos)
#define KC 128               // gemm k-chunk

typedef __attribute__((ext_vector_type(8))) short short8v;
typedef __attribute__((ext_vector_type(4))) float f32x4;

__device__ __forceinline__ unsigned short f2bf(float f) {
  unsigned u = __float_as_uint(f);
  unsigned r = (u + 0x7FFFu + ((u >> 16) & 1u)) >> 16;   // RNE
  return (unsigned short)r;
}

__device__ __forceinline__ void gload_lds16(const void* g, void* l) {
  __builtin_amdgcn_global_load_lds(
      (const __attribute__((address_space(1))) void*)g,
      (__attribute__((address_space(3))) void*)l, 16, 0, 0);
}

// ---------------- Kernel 0: wT[e][k] = bf16(w[k][e]); zero proxyacc ----------------
__global__ __launch_bounds__(256) void k_prep(const float* __restrict__ w,
                                              unsigned short* __restrict__ wT,
                                              float* __restrict__ proxyacc) {
  int gid = blockIdx.x * 256 + threadIdx.x;   // 65536 total
  int e = gid >> 10, k = gid & 1023;
  wT[gid] = f2bf(w[k * E + e]);
  if (blockIdx.x == 0) {
    proxyacc[threadIdx.x] = 0.f;
    proxyacc[threadIdx.x + 256] = 0.f;
  }
}

// ---------------- Kernel 1: logits = x @ w via bf16 MFMA ----------------
// 256 blocks x 256 thr (4 waves). Block: 64 tokens x 64 experts, K-loop in
// chunks of 128, double-buffered global_load_lds (linear LDS dest, XOR-swizzled
// global source so swizzled ds_read_b128 is bank-conflict-free).
// Wave wv: tokens 16*wv..16*wv+15, all 64 experts (4 n-frags).
// A-frag lane l: row = l&15, k = (l>>4)*8 + j. B-frag lane l: col = l&15, same k.
// C/D lane l: col = l&15, row = (l>>4)*4 + reg.
__global__ __launch_bounds__(256, 1) void k_gemm(const float* __restrict__ x,
                                                 const unsigned short* __restrict__ wT,
                                                 float* __restrict__ logits) {
  __shared__ float As[2][64 * KC];            // 2 x 32 KB
  __shared__ unsigned short Bs[2][64 * KC];   // 2 x 16 KB
  const int tid = threadIdx.x;
  const int m0 = blockIdx.x * 64;
  const int l = tid & 63;
  const int wv = tid >> 6;
  const int h = l >> 4;        // k-group 0..3
  const int r = l & 15;
  const int x7 = l & 7;        // swizzle mask for reads

  f32x4 acc[4];
#pragma unroll
  for (int f = 0; f < 4; ++f) acc[f] = (f32x4){0.f, 0.f, 0.f, 0.f};

#define STAGE(BUF, KCOFF)                                                          \
  {                                                                                \
    _Pragma("unroll") for (int i = 0; i < 8; ++i) {                                \
      int flat = tid + 256 * i;                                                    \
      int row = flat >> 5, slot = flat & 31;                                       \
      const float* g = x + (size_t)(m0 + row) * D + (KCOFF) + 4 * (slot ^ (row & 7)); \
      gload_lds16(g, (char*)&As[BUF][0] + (flat >> 6) * 1024);                     \
    }                                                                              \
    _Pragma("unroll") for (int i = 0; i < 4; ++i) {                                \
      int flat = tid + 256 * i;                                                    \
      int e = flat >> 4, slot = flat & 15;                                         \
      const unsigned short* g = wT + (size_t)e * D + (KCOFF) + 8 * (slot ^ (e & 7)); \
      gload_lds16(g, (char*)&Bs[BUF][0] + (flat >> 6) * 1024);                     \
    }                                                                              \
  }

  STAGE(0, 0);
  __syncthreads();   // drains vmcnt(0): chunk 0 resident
  int buf = 0;
  for (int c = 0; c < 8; ++c) {
    if (c < 7) STAGE(buf ^ 1, (c + 1) * KC);   // prefetch overlaps compute
    const float* arow = &As[buf][(16 * wv + r) * KC];
#pragma unroll
    for (int s = 0; s < 4; ++s) {
      int a0 = (8 * s + 2 * h) ^ x7;
      f32x4 u = *(const f32x4*)(arow + 4 * a0);
      f32x4 v = *(const f32x4*)(arow + 4 * (a0 ^ 1));
      short8v av;
      av[0] = (short)f2bf(u.x); av[1] = (short)f2bf(u.y);
      av[2] = (short)f2bf(u.z); av[3] = (short)f2bf(u.w);
      av[4] = (short)f2bf(v.x); av[5] = (short)f2bf(v.y);
      av[6] = (short)f2bf(v.z); av[7] = (short)f2bf(v.w);
      int qe = (4 * s + h) ^ x7;
#pragma unroll
      for (int f = 0; f < 4; ++f) {
        const unsigned short* brow = &Bs[buf][(16 * f + r) * KC];
        short8v bv = *(const short8v*)(brow + 8 * qe);
        acc[f] = __builtin_amdgcn_mfma_f32_16x16x32_bf16(av, bv, acc[f], 0, 0, 0);
      }
    }
    __syncthreads();   // all reads of buf done + prefetch (vmcnt) drained
    buf ^= 1;
  }

  const int token0 = m0 + 16 * wv + 4 * h;
#pragma unroll
  for (int f = 0; f < 4; ++f)
#pragma unroll
    for (int rr = 0; rr < 4; ++rr)
      logits[(size_t)(token0 + rr) * E + 16 * f + r] = acc[f][rr];
#undef STAGE
}

// ------------- Kernel 2: softmax, top-2, routing decision, z/proxy -------------
__global__ __launch_bounds__(256) void k_gate(const float* __restrict__ logits,
                                              const float* __restrict__ noise,
                                              int* __restrict__ i1o, int* __restrict__ i2o,
                                              float* __restrict__ g1o, float* __restrict__ g2o,
                                              float* __restrict__ proxyacc,
                                              float* __restrict__ zpart) {
  const int wave = threadIdx.x >> 6;
  const int lane = threadIdx.x & 63;
  const int token = (blockIdx.x << 2) + wave;

  float l = logits[(size_t)token * E + lane];
  float m = l;
#pragma unroll
  for (int off = 32; off > 0; off >>= 1) m = fmaxf(m, __shfl_xor(m, off));
  float pe = expf(l - m);
  float s = pe;
#pragma unroll
  for (int off = 32; off > 0; off >>= 1) s += __shfl_xor(s, off);

  float m1 = pe;
#pragma unroll
  for (int off = 32; off > 0; off >>= 1) m1 = fmaxf(m1, __shfl_xor(m1, off));
  int c1 = (pe == m1) ? lane : E;
#pragma unroll
  for (int off = 32; off > 0; off >>= 1) c1 = min(c1, __shfl_xor(c1, off));

  float pe2 = (lane == c1) ? -1.f : pe;
  float m2 = pe2;
#pragma unroll
  for (int off = 32; off > 0; off >>= 1) m2 = fmaxf(m2, __shfl_xor(m2, off));
  int c2 = (pe2 == m2) ? lane : E;
#pragma unroll
  for (int off = 32; off > 0; off >>= 1) c2 = min(c2, __shfl_xor(c2, off));

  float g1 = m1 / s;
  float g2 = m2 / s;
  float denom = g1 + g2 + 1e-9f;
  float g1n = g1 / denom;
  float g2n = g2 / denom;
  bool route = noise[token] < (g2n / 0.2f);

  if (lane == 0) {
    i1o[token] = c1;
    i2o[token] = route ? c2 : -1;
    g1o[token] = g1n;
    g2o[token] = g2n;
  }

  float lse = m + logf(s);
  float zsq = lse * lse;

  __shared__ float sm[4][64];
  __shared__ float zz[4];
  sm[wave][lane] = pe / s;
  if (lane == 0) zz[wave] = zsq;
  __syncthreads();
  if (wave == 0) {
    float sum4 = sm[0][lane] + sm[1][lane] + sm[2][lane] + sm[3][lane];
    atomicAdd(&proxyacc[(token >> 11) * E + lane], sum4);
    if (lane == 0) zpart[blockIdx.x] = zz[0] + zz[1] + zz[2] + zz[3];
  }
}

// ------------- Kernel 3: hierarchical parallel positions -> packed tokinfo -------------
__global__ __launch_bounds__(1024) void k_pos(const int* __restrict__ i1,
                                              const int* __restrict__ i2r,
                                              const float* __restrict__ g1,
                                              const float* __restrict__ g2,
                                              int4* __restrict__ tokinfo,
                                              int* __restrict__ count1) {
  __shared__ unsigned char pos1c[NTOK];
  __shared__ unsigned char pos2c[NTOK];
  __shared__ int cnt1[CHUNKS][E];
  __shared__ int cnt2[CHUNKS][E];

  const int b = blockIdx.x;
  const int tid = threadIdx.x;
  const int wave = tid >> 6;
  const int lane = tid & 63;
  const unsigned long long lt = (lane == 63) ? 0x7FFFFFFFFFFFFFFFull
                                             : ((1ull << lane) - 1ull);

#pragma unroll
  for (int ci = 0; ci < 2; ++ci) {
    const int c = wave * 2 + ci;
    const int base = c * CHTOK;
    int e1 = i1[b * NTOK + base + lane];
    int e2 = i2r[b * NTOK + base + lane];
    int p1 = 0, p2 = 0, myc1 = 0, myc2 = 0;
    for (int e = 0; e < E; ++e) {
      unsigned long long m1 = __ballot(e1 == e);
      unsigned long long m2 = __ballot(e2 == e);
      if (e1 == e) p1 = __popcll(m1 & lt);
      if (e2 == e) p2 = __popcll(m2 & lt);
      if (lane == e) { myc1 = __popcll(m1); myc2 = __popcll(m2); }
    }
    pos1c[base + lane] = (unsigned char)p1;
    pos2c[base + lane] = (unsigned char)p2;
    cnt1[c][lane] = myc1;
    cnt2[c][lane] = myc2;
  }
  __syncthreads();

  if (tid < E) {
    int run1 = 0, run2 = 0;
#pragma unroll 4
    for (int c = 0; c < CHUNKS; ++c) {
      int v1 = cnt1[c][tid]; cnt1[c][tid] = run1; run1 += v1;
      int v2 = cnt2[c][tid]; cnt2[c][tid] = run2; run2 += v2;
    }
    count1[b * E + tid] = run1;   // pre-capacity top-1 totals (density_1)
  }
  __syncthreads();

#pragma unroll
  for (int ci = 0; ci < 2; ++ci) {
    const int c = wave * 2 + ci;
    const int base = c * CHTOK;
    const int t = b * NTOK + base + lane;
    int e1 = i1[t];
    int e2 = i2r[t];
    int pp1 = cnt1[c][e1] + (int)pos1c[base + lane];
    int w1 = (pp1 < CAP) ? e1 * CAP + pp1 : -1;
    int w2 = -1;
    if (e2 >= 0) {
      int pp2 = cnt2[c][e2] + (int)pos2c[base + lane];
      if (pp2 < CAP) w2 = e2 * CAP + pp2;
    }
    tokinfo[t] = make_int4(w1, w2, __float_as_int(g1[t]), __float_as_int(g2[t]));
  }
}

// ------------- Kernel 4: row-owned write of dispatch+combine (fill+scatter fused) -------------
// One block per token-row; writes all 2x2560 floats (zeros except <=2 slots).
// Block 0 additionally finalizes the two scalar losses.
__global__ __launch_bounds__(256) void k_rowwrite(const int4* __restrict__ tokinfo,
                                                  const float* __restrict__ zpart,
                                                  const float* __restrict__ proxyacc,
                                                  const int* __restrict__ count1,
                                                  float* __restrict__ out) {
  const int t = blockIdx.x;
  const int tid = threadIdx.x;
  int4 ti = tokinfo[t];
  float g1v = __int_as_float(ti.z);
  float g2v = __int_as_float(ti.w);
  float4* drow = reinterpret_cast<float4*>(out) + (size_t)t * 640;
  float4* crow = reinterpret_cast<float4*>(out) + OUT_TENSOR / 4 + (size_t)t * 640;
#pragma unroll
  for (int i = 0; i < 3; ++i) {
    int idx = tid + 256 * i;
    if (idx < 640) {
      int base = idx << 2;
      float c0 = (ti.x == base)     ? g1v : (ti.y == base)     ? g2v : 0.f;
      float c1 = (ti.x == base + 1) ? g1v : (ti.y == base + 1) ? g2v : 0.f;
      float c2 = (ti.x == base + 2) ? g1v : (ti.y == base + 2) ? g2v : 0.f;
      float c3 = (ti.x == base + 3) ? g1v : (ti.y == base + 3) ? g2v : 0.f;
      crow[idx] = make_float4(c0, c1, c2, c3);
      drow[idx] = make_float4(c0 != 0.f ? 1.f : 0.f, c1 != 0.f ? 1.f : 0.f,
                              c2 != 0.f ? 1.f : 0.f, c3 != 0.f ? 1.f : 0.f);
    }
  }

  if (t == 0) {
    __shared__ float red[256];
    float zs = 0.f;
    for (int i = tid; i < 4096; i += 256) zs += zpart[i];
    red[tid] = zs;
    __syncthreads();
    for (int s = 128; s > 0; s >>= 1) {
      if (tid < s) red[tid] += red[tid + s];
      __syncthreads();
    }
    float ztot = red[0];
    __syncthreads();
    float bs = 0.f;
    for (int i = tid; i < 512; i += 256) bs += proxyacc[i] * (float)count1[i];
    red[tid] = bs;
    __syncthreads();
    for (int s = 128; s > 0; s >>= 1) {
      if (tid < s) red[tid] += red[tid + s];
      __syncthreads();
    }
    if (tid == 0) {
      out[2 * OUT_TENSOR] = red[0] / 524288.f;      // balance_loss
      out[2 * OUT_TENSOR + 1] = ztot / 16384.f;     // router_z_loss
    }
  }
}

extern "C" void kernel_launch(void* const* d_in, const int* in_sizes, int n_in,
                              void* d_out, int out_size, void* d_ws, size_t ws_size,
                              hipStream_t stream) {
  const float* x = (const float*)d_in[0];
  const float* w = (const float*)d_in[1];
  const float* noise = (const float*)d_in[2];
  float* out = (float*)d_out;

  float* ws = (float*)d_ws;
  float* logits = ws;                          // 1,048,576 floats
  int* i1 = (int*)(ws + 1048576);              // 16384
  int* i2r = i1 + TOKENS;                      // 16384
  float* g1 = (float*)(i2r + TOKENS);          // 16384
  float* g2 = g1 + TOKENS;                     // 16384
  float* proxyacc = (float*)(g2 + TOKENS);     // 512
  int* count1 = (int*)(proxyacc + 512);        // 512
  float* zpart = (float*)(count1 + 512);       // 4096
  unsigned short* wT = (unsigned short*)(zpart + 4096);   // 65536 ushorts (32768 floats)
  int4* tokinfo = (int4*)(zpart + 4096 + 32768);           // 16384 int4 (16B-aligned)

  k_prep<<<256, 256, 0, stream>>>(w, wT, proxyacc);
  k_gemm<<<256, 256, 0, stream>>>(x, wT, logits);
  k_gate<<<TOKENS / 4, 256, 0, stream>>>(logits, noise, i1, i2r, g1, g2, proxyacc, zpart);
  k_pos<<<NB, 1024, 0, stream>>>(i1, i2r, g1, g2, tokinfo, count1);
  k_rowwrite<<<TOKENS, 256, 0, stream>>>(tokinfo, zpart, proxyacc, count1, out);
}

// Round 6
// 132.426 us; speedup vs baseline: 2.9301x; 1.0472x over previous
//
#include <hip/hip_runtime.h>
#include <cstdint>
#include <cstddef>

#define NB 8
#define NTOK 2048
#define TOKENS (NB * NTOK)   // 16384
#define D 1024
#define E 64
#define CAP 40
#define EC (E * CAP)         // 2560
#define OUT_TENSOR ((size_t)TOKENS * EC)  // 41943040
#define CHUNKS 32            // per batch (k_pos)
#define CHTOK 64             // tokens per chunk (k_pos)
#define KC 64                // gemm k-chunk

#define TOTAL_F4 ((2 * OUT_TENSOR) / 4)   // 20,971,520 float4
#define S2 11534336ull       // fill boundary after K2 (55%)
#define S3 15728640ull       // fill boundary after K3 (+20%); K4 does the rest

typedef __attribute__((ext_vector_type(8))) short short8v;
typedef __attribute__((ext_vector_type(4))) float f32x4;

__device__ __forceinline__ unsigned short f2bf(float f) {
  unsigned u = __float_as_uint(f);
  unsigned r = (u + 0x7FFFu + ((u >> 16) & 1u)) >> 16;   // RNE
  return (unsigned short)r;
}

__device__ __forceinline__ void gload_lds16(const void* g, void* l) {
  __builtin_amdgcn_global_load_lds(
      (const __attribute__((address_space(1))) void*)g,
      (__attribute__((address_space(3))) void*)l, 16, 0, 0);
}

// ---------------- Kernel 0: wT[e][k] = bf16(w[k][e]); zero proxyacc ----------------
__global__ __launch_bounds__(256) void k_prep(const float* __restrict__ w,
                                              unsigned short* __restrict__ wT,
                                              float* __restrict__ proxyacc) {
  int gid = blockIdx.x * 256 + threadIdx.x;   // 65536 total
  int e = gid >> 10, k = gid & 1023;
  wT[gid] = f2bf(w[k * E + e]);
  if (blockIdx.x == 0) {
    proxyacc[threadIdx.x] = 0.f;
    proxyacc[threadIdx.x + 256] = 0.f;
  }
}

// ---------------- Kernel 1: [bf16-MFMA gemm blocks || zero-fill blocks] ----------------
// Blocks 0..255: logits = x @ w. Same fragment derivation as validated round-5
// kernel, K-chunk halved to 64 (16 chunks, double-buffered) so LDS = 48 KB and
// fill blocks get 3 blocks/CU. Operand values and k-accumulation order are
// identical -> logits bit-identical to round 5.
// Blocks 256..1023: fill out[0 .. S2) float4s with zeros.
__global__ __launch_bounds__(256, 1) void k_gemm_fill(const float* __restrict__ x,
                                                      const unsigned short* __restrict__ wT,
                                                      float* __restrict__ logits,
                                                      float* __restrict__ out) {
  __shared__ float As[2][64 * KC];            // 2 x 16 KB
  __shared__ unsigned short Bs[2][64 * KC];   // 2 x 8 KB
  const int tid = threadIdx.x;

  if (blockIdx.x >= 256) {
    float4* o4 = reinterpret_cast<float4*>(out);
    const size_t start = (size_t)(blockIdx.x - 256) * 256 + tid;
    const size_t stride = 768 * 256;
    float4 z = make_float4(0.f, 0.f, 0.f, 0.f);
    for (size_t q = start; q < S2; q += stride) o4[q] = z;
    return;
  }

  const int m0 = blockIdx.x * 64;
  const int l = tid & 63;
  const int wv = tid >> 6;
  const int h = l >> 4;        // k-group 0..3
  const int r = l & 15;
  const int x7 = l & 7;        // swizzle mask

  f32x4 acc[4];
#pragma unroll
  for (int f = 0; f < 4; ++f) acc[f] = (f32x4){0.f, 0.f, 0.f, 0.f};

#define STAGE(BUF, KCOFF)                                                           \
  {                                                                                 \
    _Pragma("unroll") for (int i = 0; i < 4; ++i) {                                 \
      int flat = tid + 256 * i;            /* 0..1023: 64 rows x 16 slots */        \
      int row = flat >> 4, slot = flat & 15;                                        \
      const float* g = x + (size_t)(m0 + row) * D + (KCOFF) + 4 * (slot ^ (row & 7)); \
      gload_lds16(g, (char*)&As[BUF][0] + (flat >> 6) * 1024);                      \
    }                                                                               \
    _Pragma("unroll") for (int i = 0; i < 2; ++i) {                                 \
      int flat = tid + 256 * i;            /* 0..511: 64 experts x 8 slots */       \
      int e = flat >> 3, slot = flat & 7;                                           \
      const unsigned short* g = wT + (size_t)e * D + (KCOFF) + 8 * (slot ^ (e & 7)); \
      gload_lds16(g, (char*)&Bs[BUF][0] + (flat >> 6) * 1024);                      \
    }                                                                               \
  }

  STAGE(0, 0);
  __syncthreads();
  int buf = 0;
  for (int c = 0; c < 16; ++c) {
    if (c < 15) STAGE(buf ^ 1, (c + 1) * KC);
    const float* arow = &As[buf][(16 * wv + r) * KC];
#pragma unroll
    for (int s = 0; s < 2; ++s) {
      int a0 = (8 * s + 2 * h) ^ x7;
      f32x4 u = *(const f32x4*)(arow + 4 * a0);
      f32x4 v = *(const f32x4*)(arow + 4 * (a0 ^ 1));
      short8v av;
      av[0] = (short)f2bf(u.x); av[1] = (short)f2bf(u.y);
      av[2] = (short)f2bf(u.z); av[3] = (short)f2bf(u.w);
      av[4] = (short)f2bf(v.x); av[5] = (short)f2bf(v.y);
      av[6] = (short)f2bf(v.z); av[7] = (short)f2bf(v.w);
      int qe = (4 * s + h) ^ x7;
#pragma unroll
      for (int f = 0; f < 4; ++f) {
        const unsigned short* brow = &Bs[buf][(16 * f + r) * KC];
        short8v bv = *(const short8v*)(brow + 8 * qe);
        acc[f] = __builtin_amdgcn_mfma_f32_16x16x32_bf16(av, bv, acc[f], 0, 0, 0);
      }
    }
    __syncthreads();
    buf ^= 1;
  }

  const int token0 = m0 + 16 * wv + 4 * h;
#pragma unroll
  for (int f = 0; f < 4; ++f)
#pragma unroll
    for (int rr = 0; rr < 4; ++rr)
      logits[(size_t)(token0 + rr) * E + 16 * f + r] = acc[f][rr];
#undef STAGE
}

// ------------- Kernel 2: [gate blocks || fill blocks] -------------
__global__ __launch_bounds__(256) void k_gate_fill(const float* __restrict__ logits,
                                                   const float* __restrict__ noise,
                                                   int* __restrict__ i1o, int* __restrict__ i2o,
                                                   float* __restrict__ g1o, float* __restrict__ g2o,
                                                   float* __restrict__ proxyacc,
                                                   float* __restrict__ zpart,
                                                   float* __restrict__ out) {
  if (blockIdx.x >= 4096) {
    float4* o4 = reinterpret_cast<float4*>(out);
    const size_t start = S2 + (size_t)(blockIdx.x - 4096) * 256 + threadIdx.x;
    const size_t stride = 1024 * 256;
    float4 z = make_float4(0.f, 0.f, 0.f, 0.f);
    for (size_t q = start; q < S3; q += stride) o4[q] = z;
    return;
  }
  const int wave = threadIdx.x >> 6;
  const int lane = threadIdx.x & 63;
  const int token = (blockIdx.x << 2) + wave;

  float l = logits[(size_t)token * E + lane];
  float m = l;
#pragma unroll
  for (int off = 32; off > 0; off >>= 1) m = fmaxf(m, __shfl_xor(m, off));
  float pe = expf(l - m);
  float s = pe;
#pragma unroll
  for (int off = 32; off > 0; off >>= 1) s += __shfl_xor(s, off);

  float m1 = pe;
#pragma unroll
  for (int off = 32; off > 0; off >>= 1) m1 = fmaxf(m1, __shfl_xor(m1, off));
  int c1 = (pe == m1) ? lane : E;
#pragma unroll
  for (int off = 32; off > 0; off >>= 1) c1 = min(c1, __shfl_xor(c1, off));

  float pe2 = (lane == c1) ? -1.f : pe;
  float m2 = pe2;
#pragma unroll
  for (int off = 32; off > 0; off >>= 1) m2 = fmaxf(m2, __shfl_xor(m2, off));
  int c2 = (pe2 == m2) ? lane : E;
#pragma unroll
  for (int off = 32; off > 0; off >>= 1) c2 = min(c2, __shfl_xor(c2, off));

  float g1 = m1 / s;
  float g2 = m2 / s;
  float denom = g1 + g2 + 1e-9f;
  float g1n = g1 / denom;
  float g2n = g2 / denom;
  bool route = noise[token] < (g2n / 0.2f);

  if (lane == 0) {
    i1o[token] = c1;
    i2o[token] = route ? c2 : -1;
    g1o[token] = g1n;
    g2o[token] = g2n;
  }

  float lse = m + logf(s);
  float zsq = lse * lse;

  __shared__ float sm[4][64];
  __shared__ float zz[4];
  sm[wave][lane] = pe / s;
  if (lane == 0) zz[wave] = zsq;
  __syncthreads();
  if (wave == 0) {
    float sum4 = sm[0][lane] + sm[1][lane] + sm[2][lane] + sm[3][lane];
    atomicAdd(&proxyacc[(token >> 11) * E + lane], sum4);
    if (lane == 0) zpart[blockIdx.x] = zz[0] + zz[1] + zz[2] + zz[3];
  }
}

// ------------- Kernel 3: [pos blocks || fill blocks] -------------
__global__ __launch_bounds__(1024) void k_pos_fill(const int* __restrict__ i1,
                                                   const int* __restrict__ i2r,
                                                   const float* __restrict__ g1,
                                                   const float* __restrict__ g2,
                                                   int4* __restrict__ tokinfo,
                                                   int* __restrict__ count1,
                                                   float* __restrict__ out) {
  if (blockIdx.x >= NB) {
    float4* o4 = reinterpret_cast<float4*>(out);
    const size_t start = S3 + (size_t)(blockIdx.x - NB) * 1024 + threadIdx.x;
    const size_t stride = 512 * 1024;
    float4 z = make_float4(0.f, 0.f, 0.f, 0.f);
    for (size_t q = start; q < TOTAL_F4; q += stride) o4[q] = z;
    return;
  }
  __shared__ unsigned char pos1c[NTOK];
  __shared__ unsigned char pos2c[NTOK];
  __shared__ int cnt1[CHUNKS][E];
  __shared__ int cnt2[CHUNKS][E];

  const int b = blockIdx.x;
  const int tid = threadIdx.x;
  const int wave = tid >> 6;
  const int lane = tid & 63;
  const unsigned long long lt = (lane == 63) ? 0x7FFFFFFFFFFFFFFFull
                                             : ((1ull << lane) - 1ull);

#pragma unroll
  for (int ci = 0; ci < 2; ++ci) {
    const int c = wave * 2 + ci;
    const int base = c * CHTOK;
    int e1 = i1[b * NTOK + base + lane];
    int e2 = i2r[b * NTOK + base + lane];
    int p1 = 0, p2 = 0, myc1 = 0, myc2 = 0;
    for (int e = 0; e < E; ++e) {
      unsigned long long m1 = __ballot(e1 == e);
      unsigned long long m2 = __ballot(e2 == e);
      if (e1 == e) p1 = __popcll(m1 & lt);
      if (e2 == e) p2 = __popcll(m2 & lt);
      if (lane == e) { myc1 = __popcll(m1); myc2 = __popcll(m2); }
    }
    pos1c[base + lane] = (unsigned char)p1;
    pos2c[base + lane] = (unsigned char)p2;
    cnt1[c][lane] = myc1;
    cnt2[c][lane] = myc2;
  }
  __syncthreads();

  if (tid < E) {
    int run1 = 0, run2 = 0;
#pragma unroll 4
    for (int c = 0; c < CHUNKS; ++c) {
      int v1 = cnt1[c][tid]; cnt1[c][tid] = run1; run1 += v1;
      int v2 = cnt2[c][tid]; cnt2[c][tid] = run2; run2 += v2;
    }
    count1[b * E + tid] = run1;   // pre-capacity top-1 totals (density_1)
  }
  __syncthreads();

#pragma unroll
  for (int ci = 0; ci < 2; ++ci) {
    const int c = wave * 2 + ci;
    const int base = c * CHTOK;
    const int t = b * NTOK + base + lane;
    int e1 = i1[t];
    int e2 = i2r[t];
    int pp1 = cnt1[c][e1] + (int)pos1c[base + lane];
    int w1 = (pp1 < CAP) ? e1 * CAP + pp1 : -1;
    int w2 = -1;
    if (e2 >= 0) {
      int pp2 = cnt2[c][e2] + (int)pos2c[base + lane];
      if (pp2 < CAP) w2 = e2 * CAP + pp2;
    }
    tokinfo[t] = make_int4(w1, w2, __float_as_int(g1[t]), __float_as_int(g2[t]));
  }
}

// ------------- Kernel 4: sparse scatter + scalar losses -------------
__global__ __launch_bounds__(256) void k_scatter_final(const int4* __restrict__ tokinfo,
                                                       const float* __restrict__ zpart,
                                                       const float* __restrict__ proxyacc,
                                                       const int* __restrict__ count1,
                                                       float* __restrict__ out) {
  const int t = blockIdx.x * 256 + threadIdx.x;
  const int tid = threadIdx.x;
  if (t < TOKENS) {
    int4 ti = tokinfo[t];
    float* dispatch = out;
    float* combine = out + OUT_TENSOR;
    if (ti.x >= 0) {
      size_t off = (size_t)t * EC + ti.x;
      combine[off] = __int_as_float(ti.z);
      dispatch[off] = 1.f;          // g1n > 0 always
    }
    if (ti.y >= 0) {
      size_t off = (size_t)t * EC + ti.y;
      combine[off] = __int_as_float(ti.w);
      dispatch[off] = 1.f;          // g2n > 0 always
    }
  }

  if (blockIdx.x == 0) {
    __shared__ float red[256];
    float zs = 0.f;
    for (int i = tid; i < 4096; i += 256) zs += zpart[i];
    red[tid] = zs;
    __syncthreads();
    for (int s = 128; s > 0; s >>= 1) {
      if (tid < s) red[tid] += red[tid + s];
      __syncthreads();
    }
    float ztot = red[0];
    __syncthreads();
    float bs = 0.f;
    for (int i = tid; i < 512; i += 256) bs += proxyacc[i] * (float)count1[i];
    red[tid] = bs;
    __syncthreads();
    for (int s = 128; s > 0; s >>= 1) {
      if (tid < s) red[tid] += red[tid + s];
      __syncthreads();
    }
    if (tid == 0) {
      out[2 * OUT_TENSOR] = red[0] / 524288.f;      // balance_loss
      out[2 * OUT_TENSOR + 1] = ztot / 16384.f;     // router_z_loss
    }
  }
}

extern "C" void kernel_launch(void* const* d_in, const int* in_sizes, int n_in,
                              void* d_out, int out_size, void* d_ws, size_t ws_size,
                              hipStream_t stream) {
  const float* x = (const float*)d_in[0];
  const float* w = (const float*)d_in[1];
  const float* noise = (const float*)d_in[2];
  float* out = (float*)d_out;

  float* ws = (float*)d_ws;
  float* logits = ws;                          // 1,048,576 floats
  int* i1 = (int*)(ws + 1048576);              // 16384
  int* i2r = i1 + TOKENS;                      // 16384
  float* g1 = (float*)(i2r + TOKENS);          // 16384
  float* g2 = g1 + TOKENS;                     // 16384
  float* proxyacc = (float*)(g2 + TOKENS);     // 512
  int* count1 = (int*)(proxyacc + 512);        // 512
  float* zpart = (float*)(count1 + 512);       // 4096
  unsigned short* wT = (unsigned short*)(zpart + 4096);   // 65536 ushorts
  int4* tokinfo = (int4*)(zpart + 4096 + 32768);           // 16384 int4

  k_prep<<<256, 256, 0, stream>>>(w, wT, proxyacc);
  k_gemm_fill<<<1024, 256, 0, stream>>>(x, wT, logits, out);
  k_gate_fill<<<5120, 256, 0, stream>>>(logits, noise, i1, i2r, g1, g2, proxyacc, zpart, out);
  k_pos_fill<<<NB + 512, 1024, 0, stream>>>(i1, i2r, g1, g2, tokinfo, count1, out);
  k_scatter_final<<<64, 256, 0, stream>>>(tokinfo, zpart, proxyacc, count1, out);
}